// Round 2
// baseline (555.560 us; speedup 1.0000x reference)
//
#include <hip/hip_runtime.h>
#include <stdint.h>

// ---------------------------------------------------------------------------
// NodeDropout: drop-set = jax.random.permutation(key(42), 200000)[:20000],
// keep edge unless BOTH endpoints dropped, stable-compact kept edges, -1 tail.
// Exact JAX Threefry-2x32, *partitionable* (JAX >= 0.4.30 default) semantics:
//   split:      pair j = (0, j); keys[j] = (out0, out1)
//   bits32[i]   = out0 ^ out1 of counter (0, i)
// 2-round sort-shuffle replicated via stable ranks.
// ---------------------------------------------------------------------------

#define N_NODES   200000
#define N_DROP    20000
#define NEDGE     20000000
#define NBIN      65536
#define NWORDS_ND 6250          // 200000/32

// edge-pass geometry
#define EB_T      256
#define EB_VEC    4
#define EB_IT     8
#define EB_EDGES  (EB_T*EB_VEC*EB_IT)               // 8192
#define EB_NB     ((NEDGE + EB_EDGES - 1)/EB_EDGES) // 2442

// ---- workspace layout (bytes). Zeroed region: [0, ZERO_BYTES) ----
#define OFS_HIST1   0u
#define OFS_HIST2   262144u
#define OFS_CNT1    524288u
#define OFS_SCAL    786432u     // u64 slots: 0=B 1=r 2=T 3=candCount 4=nKeep
#define ZERO_BYTES  787456u
#define OFS_OFFS1   787456u
#define OFS_BITS1   1049600u
#define OFS_BITS2   1849600u
#define OFS_RANK1   2649600u
#define OFS_SORT1   3449600u
#define OFS_CAND    5049600u    // 4096 u64
#define OFS_DROPB   5082368u    // 6250 u32 node drop bits
#define OFS_BLKCNT  5107392u
#define OFS_BLKOFF  5117184u
#define OFS_KEEPB   5126976u    // EB_NB*256 u32 edge keep bits
// total = 5126976 + 2442*256*4 = 7,627,584 bytes

struct U2pair { uint32_t a, b; };

// Threefry-2x32, 20 rounds — exact JAX/Random123 schedule.
__host__ __device__ constexpr U2pair tf2x32(uint32_t k0, uint32_t k1,
                                            uint32_t x0, uint32_t x1) {
  uint32_t ks[3] = { k0, k1, 0x1BD11BDAu ^ k0 ^ k1 };
  uint32_t v0 = x0 + ks[0];
  uint32_t v1 = x1 + ks[1];
  const int rotA[4] = {13, 15, 26, 6};
  const int rotB[4] = {17, 29, 16, 24};
  for (int i = 0; i < 5; ++i) {
    for (int j = 0; j < 4; ++j) {
      const int r = (i & 1) ? rotB[j] : rotA[j];
      v0 += v1;
      v1 = (v1 << r) | (v1 >> (32 - r));
      v1 ^= v0;
    }
    v0 += ks[(i + 1) % 3];
    v1 += ks[(i + 2) % 3] + (uint32_t)(i + 1);
  }
  return U2pair{v0, v1};
}

// Partitionable key chain from key(42) = (0,42):
//   split #1: keys[j] = tf(key, 0, j).  carried = keys[0], use1 = keys[1]
//   split #2 on carried: use2 = tf(carried, 0, 1)
constexpr U2pair CARRY1 = tf2x32(0u, 42u, 0u, 0u);
constexpr U2pair USE1   = tf2x32(0u, 42u, 0u, 1u);
constexpr uint32_t UK1A = USE1.a, UK1B = USE1.b;
constexpr U2pair USE2   = tf2x32(CARRY1.a, CARRY1.b, 0u, 1u);
constexpr uint32_t UK2A = USE2.a, UK2B = USE2.b;

// ---------------------------------------------------------------------------
// K1: bits1/bits2 for all 200000 positions + 16-bit-bucket histograms.
// Partitionable random_bits: bits[i] = out0 ^ out1 of counter (0, i).
__global__ void k_bits_hist(uint32_t* __restrict__ bits1,
                            uint32_t* __restrict__ bits2,
                            uint32_t* __restrict__ hist1,
                            uint32_t* __restrict__ hist2) {
  const int i = blockIdx.x * blockDim.x + threadIdx.x;
  if (i >= N_NODES) return;
  const U2pair r1 = tf2x32(UK1A, UK1B, 0u, (uint32_t)i);
  const U2pair r2 = tf2x32(UK2A, UK2B, 0u, (uint32_t)i);
  const uint32_t b1 = r1.a ^ r1.b;
  const uint32_t b2 = r2.a ^ r2.b;
  bits1[i] = b1;
  bits2[i] = b2;
  atomicAdd(&hist1[b1 >> 16], 1u);
  atomicAdd(&hist2[b2 >> 16], 1u);
}

// K2: exclusive scan of a 65536-bin histogram (1 block, 1024 thr).
// If findSel: also locate the bin containing global rank N_DROP-1 and store
// (bin, rank-within-bin) to scalars[0..1].
__global__ __launch_bounds__(1024)
void k_scan_hist(const uint32_t* __restrict__ hist,
                 uint32_t* __restrict__ offs,
                 uint64_t* __restrict__ scal, int findSel) {
  __shared__ uint32_t sums[1024];
  const int t = threadIdx.x;
  uint32_t s = 0;
  for (int j = 0; j < NBIN / 1024; ++j) s += hist[t * (NBIN / 1024) + j];
  sums[t] = s;
  __syncthreads();
  for (int d = 1; d < 1024; d <<= 1) {
    const uint32_t v = sums[t];
    const uint32_t add = (t >= d) ? sums[t - d] : 0u;
    __syncthreads();
    sums[t] = v + add;
    __syncthreads();
  }
  uint32_t run = (t == 0) ? 0u : sums[t - 1];
  for (int j = 0; j < NBIN / 1024; ++j) {
    const int b = t * (NBIN / 1024) + j;
    const uint32_t c = hist[b];
    if (offs) offs[b] = run;
    if (findSel && run <= (uint32_t)(N_DROP - 1) &&
        (uint32_t)(N_DROP - 1) < run + c) {
      scal[0] = (uint64_t)b;
      scal[1] = (uint64_t)((N_DROP - 1) - run);
    }
    run += c;
  }
}

// K3: scatter round-1 composite keys into their 16-bit buckets.
__global__ void k_scatter1(const uint32_t* __restrict__ bits1,
                           const uint32_t* __restrict__ offs1,
                           uint32_t* __restrict__ cnt1,
                           uint64_t* __restrict__ sort1) {
  const int i = blockIdx.x * blockDim.x + threadIdx.x;
  if (i >= N_NODES) return;
  const uint32_t k = bits1[i];
  const uint32_t b = k >> 16;
  const uint32_t slot = atomicAdd(&cnt1[b], 1u);
  sort1[offs1[b] + slot] = ((uint64_t)k << 32) | (uint32_t)i;
}

// K4: rank1[i] = bucket offset + #smaller composite keys in bucket.
__global__ void k_rank1(const uint32_t* __restrict__ bits1,
                        const uint32_t* __restrict__ offs1,
                        const uint32_t* __restrict__ hist1,
                        const uint64_t* __restrict__ sort1,
                        uint32_t* __restrict__ rank1) {
  const int i = blockIdx.x * blockDim.x + threadIdx.x;
  if (i >= N_NODES) return;
  const uint32_t k = bits1[i];
  const uint32_t b = k >> 16;
  const uint64_t me = ((uint64_t)k << 32) | (uint32_t)i;
  const uint32_t start = offs1[b];
  const uint32_t cnt = hist1[b];
  uint32_t c = 0;
  for (uint32_t s = 0; s < cnt; ++s) c += (sort1[start + s] < me) ? 1u : 0u;
  rank1[i] = start + c;
}

// K5: gather round-2 elements living in the threshold bin.
__global__ void k_cand(const uint32_t* __restrict__ bits2,
                       const uint64_t* __restrict__ scal,
                       uint64_t* __restrict__ cand,
                       uint32_t* __restrict__ candCount) {
  const int i = blockIdx.x * blockDim.x + threadIdx.x;
  if (i >= N_NODES) return;
  const uint32_t B = (uint32_t)scal[0];
  const uint32_t k = bits2[i];
  if ((k >> 16) == B) {
    const uint32_t p = atomicAdd(candCount, 1u);
    if (p < 4096u) cand[p] = ((uint64_t)k << 32) | (uint32_t)i;
  }
}

// K6: select r-th smallest candidate -> threshold T (20000th order stat).
__global__ void k_thresh(const uint64_t* __restrict__ cand,
                         const uint32_t* __restrict__ candCount,
                         uint64_t* __restrict__ scal) {
  if (blockIdx.x != 0 || threadIdx.x != 0) return;
  const uint32_t n = *candCount;
  const uint32_t r = (uint32_t)scal[1];
  uint64_t T = 0;
  for (uint32_t a = 0; a < n; ++a) {
    const uint64_t v = cand[a];
    uint32_t c = 0;
    for (uint32_t b = 0; b < n; ++b) c += (cand[b] < v) ? 1u : 0u;
    if (c == r) { T = v; break; }
  }
  scal[2] = T;
}

// K7: node drop bits. drop[i] = K2(rank1(i)) <= T.
__global__ void k_drop(const uint32_t* __restrict__ bits2,
                       const uint32_t* __restrict__ rank1,
                       const uint64_t* __restrict__ scal,
                       uint32_t* __restrict__ dropbits) {
  const int w = blockIdx.x * blockDim.x + threadIdx.x;
  if (w >= NWORDS_ND) return;
  const uint64_t T = scal[2];
  uint32_t word = 0;
  #pragma unroll 4
  for (int j = 0; j < 32; ++j) {
    const int i = w * 32 + j;
    const uint32_t jj = rank1[i];
    const uint64_t K2 = ((uint64_t)bits2[jj] << 32) | jj;
    if (K2 <= T) word |= (1u << j);
  }
  dropbits[w] = word;
}

// K8: per-block keep counts + per-edge keep bits (int4 loads, short-circuit
// gather: item bit only read when user bit set, ~10% of lanes).
__global__ __launch_bounds__(EB_T)
void k_count(const int* __restrict__ ei,
             const uint32_t* __restrict__ dropbits,
             uint32_t* __restrict__ keepbits,
             uint32_t* __restrict__ blkcnt) {
  const int b = blockIdx.x;
  const int t = threadIdx.x;
  const int64_t blockStart = (int64_t)b * EB_EDGES;
  __shared__ uint32_t nib[EB_T];
  __shared__ uint32_t wsum[EB_T / 64];
  uint32_t myCount = 0;
  for (int k = 0; k < EB_IT; ++k) {
    const int64_t e = blockStart + (int64_t)k * (EB_T * EB_VEC) + t * EB_VEC;
    uint32_t flags = 0;
    if (e < NEDGE) {
      const int4 u4 = *(const int4*)(ei + e);
      const int4 i4 = *(const int4*)(ei + NEDGE + e);
      const int us[4] = {u4.x, u4.y, u4.z, u4.w};
      const int is_[4] = {i4.x, i4.y, i4.z, i4.w};
      #pragma unroll
      for (int j = 0; j < 4; ++j) {
        const uint32_t du = (dropbits[us[j] >> 5] >> (us[j] & 31)) & 1u;
        uint32_t keep = 1u;
        if (du) {
          const uint32_t di = (dropbits[is_[j] >> 5] >> (is_[j] & 31)) & 1u;
          keep = 1u - di;
        }
        flags |= keep << j;
      }
    }
    myCount += __popc(flags);
    nib[t] = flags;
    __syncthreads();
    if (t < 32) {
      uint32_t wd = 0;
      #pragma unroll
      for (int m = 0; m < 8; ++m) wd |= nib[t * 8 + m] << (4 * m);
      keepbits[(uint32_t)(b * 256 + k * 32 + t)] = wd;
    }
    __syncthreads();
  }
  uint32_t v = myCount;
  #pragma unroll
  for (int d = 32; d >= 1; d >>= 1) v += __shfl_down(v, d);
  if ((t & 63) == 0) wsum[t >> 6] = v;
  __syncthreads();
  if (t == 0) blkcnt[b] = wsum[0] + wsum[1] + wsum[2] + wsum[3];
}

// K9: scan of block counts (EB_NB=2442 fits one 1024-thread block).
#define SB_PER ((EB_NB + 1023) / 1024)   // 3
__global__ __launch_bounds__(1024)
void k_scan_blocks(const uint32_t* __restrict__ blkcnt,
                   uint32_t* __restrict__ blkoff,
                   uint64_t* __restrict__ scal) {
  __shared__ uint32_t sums[1024];
  const int t = threadIdx.x;
  uint32_t loc[SB_PER];
  uint32_t s = 0;
  #pragma unroll
  for (int j = 0; j < SB_PER; ++j) {
    const int idx = t * SB_PER + j;
    const uint32_t c = (idx < EB_NB) ? blkcnt[idx] : 0u;
    loc[j] = c; s += c;
  }
  sums[t] = s;
  __syncthreads();
  for (int d = 1; d < 1024; d <<= 1) {
    const uint32_t v = sums[t];
    const uint32_t add = (t >= d) ? sums[t - d] : 0u;
    __syncthreads();
    sums[t] = v + add;
    __syncthreads();
  }
  uint32_t excl = (t == 0) ? 0u : sums[t - 1];
  #pragma unroll
  for (int j = 0; j < SB_PER; ++j) {
    const int idx = t * SB_PER + j;
    if (idx < EB_NB) blkoff[idx] = excl;
    excl += loc[j];
  }
  if (t == 1023) scal[4] = (uint64_t)sums[1023];   // n_keep
}

// K10: stable scatter. Kept edge -> [keepPos]; dropped -> -1 at
// nKeep + dropRank. Every output word written exactly once.
__global__ __launch_bounds__(EB_T)
void k_scatter_out(const int* __restrict__ ei,
                   const uint32_t* __restrict__ keepbits,
                   const uint32_t* __restrict__ blkoff,
                   const uint64_t* __restrict__ scal,
                   int* __restrict__ out) {
  const int b = blockIdx.x;
  const int t = threadIdx.x;
  const int lane = t & 63;
  const int wid = t >> 6;
  const int64_t blockStart = (int64_t)b * EB_EDGES;
  const uint32_t nKeep = (uint32_t)scal[4];
  uint32_t keepBase = blkoff[b];
  uint32_t dropBase = nKeep + (uint32_t)blockStart - keepBase;
  __shared__ uint32_t wtot[EB_T / 64];
  for (int k = 0; k < EB_IT; ++k) {
    const int64_t e = blockStart + (int64_t)k * (EB_T * EB_VEC) + t * EB_VEC;
    uint32_t flags = 0, valid = 0;
    int4 u4 = make_int4(0, 0, 0, 0), i4 = make_int4(0, 0, 0, 0);
    if (e < NEDGE) {
      valid = EB_VEC;
      const uint32_t wd = keepbits[(uint32_t)(b * 256 + k * 32 + (t >> 3))];
      flags = (wd >> (4 * (t & 7))) & 0xFu;
      u4 = *(const int4*)(ei + e);
      i4 = *(const int4*)(ei + NEDGE + e);
    }
    const uint32_t c = __popc(flags);
    const uint32_t p = c | (valid << 16);
    uint32_t incl = p;
    #pragma unroll
    for (int d = 1; d < 64; d <<= 1) {
      const uint32_t o = __shfl_up(incl, (unsigned)d);
      if (lane >= d) incl += o;
    }
    if (lane == 63) wtot[wid] = incl;
    __syncthreads();
    uint32_t wpref = 0, tot = 0;
    #pragma unroll
    for (int w2 = 0; w2 < EB_T / 64; ++w2) {
      const uint32_t v = wtot[w2];
      if (w2 < wid) wpref += v;
      tot += v;
    }
    const uint32_t excl = wpref + incl - p;
    uint32_t kpos = keepBase + (excl & 0xFFFFu);
    uint32_t dpos = dropBase + ((excl >> 16) - (excl & 0xFFFFu));
    if (valid) {
      const int us[4] = {u4.x, u4.y, u4.z, u4.w};
      const int is_[4] = {i4.x, i4.y, i4.z, i4.w};
      #pragma unroll
      for (int j = 0; j < 4; ++j) {
        if ((flags >> j) & 1u) {
          out[kpos] = us[j];
          out[NEDGE + kpos] = is_[j];
          ++kpos;
        } else {
          out[dpos] = -1;
          out[NEDGE + dpos] = -1;
          ++dpos;
        }
      }
    }
    keepBase += tot & 0xFFFFu;
    dropBase += (tot >> 16) - (tot & 0xFFFFu);
    __syncthreads();
  }
}

extern "C" void kernel_launch(void* const* d_in, const int* in_sizes, int n_in,
                              void* d_out, int out_size, void* d_ws,
                              size_t ws_size, hipStream_t stream) {
  (void)in_sizes; (void)n_in; (void)out_size; (void)ws_size;
  const int* ei = (const int*)d_in[0];
  int* out = (int*)d_out;
  char* ws = (char*)d_ws;

  uint32_t* hist1 = (uint32_t*)(ws + OFS_HIST1);
  uint32_t* hist2 = (uint32_t*)(ws + OFS_HIST2);
  uint32_t* cnt1  = (uint32_t*)(ws + OFS_CNT1);
  uint64_t* scal  = (uint64_t*)(ws + OFS_SCAL);
  uint32_t* candN = (uint32_t*)(ws + OFS_SCAL + 24);  // scal[3] as u32
  uint32_t* offs1 = (uint32_t*)(ws + OFS_OFFS1);
  uint32_t* bits1 = (uint32_t*)(ws + OFS_BITS1);
  uint32_t* bits2 = (uint32_t*)(ws + OFS_BITS2);
  uint32_t* rank1 = (uint32_t*)(ws + OFS_RANK1);
  uint64_t* sort1 = (uint64_t*)(ws + OFS_SORT1);
  uint64_t* cand  = (uint64_t*)(ws + OFS_CAND);
  uint32_t* dropb = (uint32_t*)(ws + OFS_DROPB);
  uint32_t* blkcnt = (uint32_t*)(ws + OFS_BLKCNT);
  uint32_t* blkoff = (uint32_t*)(ws + OFS_BLKOFF);
  uint32_t* keepb  = (uint32_t*)(ws + OFS_KEEPB);

  hipMemsetAsync(d_ws, 0, ZERO_BYTES, stream);

  k_bits_hist<<<(N_NODES + 255) / 256, 256, 0, stream>>>(bits1, bits2, hist1, hist2);
  k_scan_hist<<<1, 1024, 0, stream>>>(hist1, offs1, scal, 0);
  k_scan_hist<<<1, 1024, 0, stream>>>(hist2, nullptr, scal, 1);
  k_scatter1<<<(N_NODES + 255) / 256, 256, 0, stream>>>(bits1, offs1, cnt1, sort1);
  k_rank1<<<(N_NODES + 255) / 256, 256, 0, stream>>>(bits1, offs1, hist1, sort1, rank1);
  k_cand<<<(N_NODES + 255) / 256, 256, 0, stream>>>(bits2, scal, cand, candN);
  k_thresh<<<1, 64, 0, stream>>>(cand, candN, scal);
  k_drop<<<(NWORDS_ND + 255) / 256, 256, 0, stream>>>(bits2, rank1, scal, dropb);
  k_count<<<EB_NB, EB_T, 0, stream>>>(ei, dropb, keepb, blkcnt);
  k_scan_blocks<<<1, 1024, 0, stream>>>(blkcnt, blkoff, scal);
  k_scatter_out<<<EB_NB, EB_T, 0, stream>>>(ei, keepb, blkoff, scal, out);
}